// Round 1
// baseline (548.731 us; speedup 1.0000x reference)
//
#include <hip/hip_runtime.h>
#include <hip/hip_bf16.h>
#include <math.h>

// ---------------------------------------------------------------------------
// TGATCell: GATv2Conv (4 heads x 32) + GRU-ish cell.
// Pipeline:
//   0. memset deg
//   1. detect edge_index dtype (int64 vs int32) on device
//   2. convert edge_index -> src32/dst32
//   3. histogram in-degree by dst
//   4. exclusive scan -> CSR offsets (+ cursor copy)
//   5. scatter src ids into CSR slots
//   6. xl = x@Wl, xr = x@Wr            (fused two-matrix GEMM)
//   7. node pass: per-node softmax-aggregate over in-edges (one wave/node)
//   8. ru = sigmoid([f,h]@W1+b1) -> rh = r*h, u
//   9. c = tanh([f,rh]@W2+b2); out = u*h + (1-u)*c
// ---------------------------------------------------------------------------

__global__ __launch_bounds__(1024) void detect_kernel(const unsigned int* __restrict__ ei,
                                                      long long n_u32, int* __restrict__ flag) {
  __shared__ int any;
  if (threadIdx.x == 0) any = 0;
  __syncthreads();
  int nz = 0;
  for (int rep = 0; rep < 4; ++rep) {
    long long idx = 2LL * (threadIdx.x + rep * 1024) + 1;  // odd u32 slots
    if (idx < n_u32 && ei[idx] != 0u) nz = 1;
  }
  if (nz) atomicOr(&any, 1);
  __syncthreads();
  if (threadIdx.x == 0) *flag = any;  // 1 -> int32 data, 0 -> int64 data
}

__global__ __launch_bounds__(256) void convert_kernel(const void* __restrict__ ei, int E,
                                                      const int* __restrict__ flag,
                                                      int* __restrict__ src32,
                                                      int* __restrict__ dst32) {
  int i = blockIdx.x * 256 + threadIdx.x;
  if (i >= E) return;
  if (*flag == 0) {  // int64
    const long long* p = (const long long*)ei;
    src32[i] = (int)p[i];
    dst32[i] = (int)p[(long long)E + i];
  } else {           // int32
    const int* p = (const int*)ei;
    src32[i] = p[i];
    dst32[i] = p[E + i];
  }
}

__global__ __launch_bounds__(256) void hist_kernel(const int* __restrict__ dst32,
                                                   int* __restrict__ deg, int E) {
  int i = blockIdx.x * 256 + threadIdx.x;
  if (i < E) atomicAdd(&deg[dst32[i]], 1);
}

// single-block exclusive scan of deg[0..n-1] -> off[0..n], cursor copy
__global__ __launch_bounds__(1024) void scan_kernel(const int* __restrict__ deg,
                                                    int* __restrict__ off,
                                                    int* __restrict__ cursor, int n) {
  __shared__ int wsum[16];
  int lane = threadIdx.x & 63, wid = threadIdx.x >> 6;
  if (threadIdx.x == 0) { off[0] = 0; cursor[0] = 0; }
  int carry = 0;
  for (int base = 0; base < n; base += 1024) {
    int i = base + (int)threadIdx.x;
    int v = (i < n) ? deg[i] : 0;
    int s = v;
    #pragma unroll
    for (int ofs = 1; ofs < 64; ofs <<= 1) {
      int t = __shfl_up(s, ofs, 64);
      if (lane >= ofs) s += t;
    }
    if (lane == 63) wsum[wid] = s;
    __syncthreads();
    int wpre = 0;
    for (int ww = 0; ww < wid; ++ww) wpre += wsum[ww];
    int incl = s + wpre + carry;
    if (i < n) { off[i + 1] = incl; cursor[i + 1] = incl; }
    int total = 0;
    for (int ww = 0; ww < 16; ++ww) total += wsum[ww];
    carry += total;
    __syncthreads();
  }
}

__global__ __launch_bounds__(256) void scatter_kernel(const int* __restrict__ src32,
                                                      const int* __restrict__ dst32,
                                                      int* __restrict__ cursor,
                                                      int* __restrict__ csr, int E) {
  int i = blockIdx.x * 256 + threadIdx.x;
  if (i >= E) return;
  int pos = atomicAdd(&cursor[dst32[i]], 1);
  csr[pos] = src32[i];
}

// xl = x@Wl, xr = x@Wr.  gridDim.y selects the weight matrix.
__global__ __launch_bounds__(256) void gemm_xw(const float* __restrict__ x,
                                               const float* __restrict__ Wl,
                                               const float* __restrict__ Wr,
                                               float* __restrict__ xl,
                                               float* __restrict__ xr, int n) {
  __shared__ float Ws[128 * 128];   // 64 KB
  __shared__ float xs[128 * 33];    // transposed x tile, padded
  const float* __restrict__ W = blockIdx.y ? Wr : Wl;
  float* __restrict__ out = blockIdx.y ? xr : xl;
  int row0 = blockIdx.x * 32;
  int t = threadIdx.x;
  {
    const float4* Wv = (const float4*)W;
    float4* Wsv = (float4*)Ws;
    #pragma unroll
    for (int rep = 0; rep < 16; ++rep) Wsv[t + rep * 256] = Wv[t + rep * 256];
  }
  #pragma unroll
  for (int rep = 0; rep < 4; ++rep) {
    int idx = t + rep * 256;
    int r = idx >> 5, k4 = idx & 31;
    int row = row0 + r;
    float4 v = make_float4(0.f, 0.f, 0.f, 0.f);
    if (row < n) v = *(const float4*)(x + (size_t)row * 128 + k4 * 4);
    xs[(k4 * 4 + 0) * 33 + r] = v.x;
    xs[(k4 * 4 + 1) * 33 + r] = v.y;
    xs[(k4 * 4 + 2) * 33 + r] = v.z;
    xs[(k4 * 4 + 3) * 33 + r] = v.w;
  }
  __syncthreads();
  int cg = t & 31, rg = t >> 5;
  int c0 = cg * 4, r0 = rg * 4;
  float acc[4][4] = {};
  #pragma unroll 8
  for (int k = 0; k < 128; ++k) {
    float xv[4], wv[4];
    #pragma unroll
    for (int i = 0; i < 4; ++i) xv[i] = xs[k * 33 + r0 + i];
    #pragma unroll
    for (int j = 0; j < 4; ++j) wv[j] = Ws[k * 128 + c0 + j];
    #pragma unroll
    for (int i = 0; i < 4; ++i)
      #pragma unroll
      for (int j = 0; j < 4; ++j) acc[i][j] = fmaf(xv[i], wv[j], acc[i][j]);
  }
  #pragma unroll
  for (int i = 0; i < 4; ++i) {
    int row = row0 + r0 + i;
    if (row < n)
      *(float4*)(out + (size_t)row * 128 + c0) =
          make_float4(acc[i][0], acc[i][1], acc[i][2], acc[i][3]);
  }
}

// One wave per node: softmax over in-edges + weighted aggregation, in registers.
__global__ __launch_bounds__(256) void node_kernel(const float* __restrict__ xl,
                                                   const float* __restrict__ xr,
                                                   const float* __restrict__ att,
                                                   const float* __restrict__ bias,
                                                   const int* __restrict__ off,
                                                   const int* __restrict__ csr,
                                                   float* __restrict__ f, int n) {
  int wid = threadIdx.x >> 6, lane = threadIdx.x & 63;
  int node = blockIdx.x * 4 + wid;
  if (node >= n) return;
  int c0 = lane, c1 = lane + 64;
  float a0 = att[c0], a1 = att[c1];
  float xr0 = xr[(size_t)node * 128 + c0];
  float xr1 = xr[(size_t)node * 128 + c1];
  float num0 = 0.f, num1 = 0.f, den0 = 0.f, den1 = 0.f;
  int beg = off[node], end = off[node + 1];
  for (int j = beg - 1; j < end; ++j) {   // j == beg-1 encodes the self loop
    int src = (j < beg) ? node : csr[j];
    float xls0 = xl[(size_t)src * 128 + c0];
    float xls1 = xl[(size_t)src * 128 + c1];
    float m0 = xls0 + xr0, m1 = xls1 + xr1;
    float l0 = m0 > 0.f ? m0 : 0.2f * m0;
    float l1 = m1 > 0.f ? m1 : 0.2f * m1;
    float p0 = l0 * a0, p1 = l1 * a1;
    // half-wave (32-lane) reductions -> per-head logits; heads: (c/32)
    #pragma unroll
    for (int mask = 1; mask < 32; mask <<= 1) {
      p0 += __shfl_xor(p0, mask, 64);
      p1 += __shfl_xor(p1, mask, 64);
    }
    float w0 = __expf(p0), w1 = __expf(p1);   // no max-subtraction: identical softmax
    num0 = fmaf(w0, xls0, num0);
    num1 = fmaf(w1, xls1, num1);
    den0 += w0;
    den1 += w1;
  }
  float v0 = num0 / (den0 + 1e-16f) + bias[c0];
  float v1 = num1 / (den1 + 1e-16f) + bias[c1];
  f[(size_t)node * 128 + c0] = 1.f / (1.f + __expf(-v0));
  f[(size_t)node * 128 + c1] = 1.f / (1.f + __expf(-v1));
}

// ru = sigmoid([f,h] @ W1 + b1); rh = r*h; u stored.
__global__ __launch_bounds__(256) void gemm_ru(const float* __restrict__ fbuf,
                                               const float* __restrict__ h,
                                               const float* __restrict__ W1,
                                               const float* __restrict__ b1,
                                               float* __restrict__ rh,
                                               float* __restrict__ u, int n) {
  __shared__ float Ws[64 * 256];   // 64 KB chunk of W1
  __shared__ float As[64 * 33];
  int row0 = blockIdx.x * 32;
  int t = threadIdx.x;
  int cg = t & 31, rg = t >> 5;
  int c0 = cg * 8, r0 = rg * 4;
  float acc[4][8] = {};
  for (int kc = 0; kc < 4; ++kc) {
    const float4* Wv = (const float4*)(W1 + (size_t)kc * 64 * 256);
    float4* Wsv = (float4*)Ws;
    #pragma unroll
    for (int rep = 0; rep < 16; ++rep) Wsv[t + rep * 256] = Wv[t + rep * 256];
    const float* __restrict__ srcp = (kc < 2) ? fbuf : h;
    int cbase = (kc & 1) * 64;
    #pragma unroll
    for (int rep = 0; rep < 2; ++rep) {
      int idx = t + rep * 256;
      int r = idx >> 4, k4 = idx & 15;
      int row = row0 + r;
      float4 v = make_float4(0.f, 0.f, 0.f, 0.f);
      if (row < n) v = *(const float4*)(srcp + (size_t)row * 128 + cbase + k4 * 4);
      As[(k4 * 4 + 0) * 33 + r] = v.x;
      As[(k4 * 4 + 1) * 33 + r] = v.y;
      As[(k4 * 4 + 2) * 33 + r] = v.z;
      As[(k4 * 4 + 3) * 33 + r] = v.w;
    }
    __syncthreads();
    #pragma unroll 4
    for (int k = 0; k < 64; ++k) {
      float xv[4];
      #pragma unroll
      for (int i = 0; i < 4; ++i) xv[i] = As[k * 33 + r0 + i];
      float4 wa = *(const float4*)&Ws[k * 256 + c0];
      float4 wb = *(const float4*)&Ws[k * 256 + c0 + 4];
      float wv[8] = {wa.x, wa.y, wa.z, wa.w, wb.x, wb.y, wb.z, wb.w};
      #pragma unroll
      for (int i = 0; i < 4; ++i)
        #pragma unroll
        for (int j = 0; j < 8; ++j) acc[i][j] = fmaf(xv[i], wv[j], acc[i][j]);
    }
    __syncthreads();
  }
  bool left = (c0 < 128);
  #pragma unroll
  for (int i = 0; i < 4; ++i) {
    int row = row0 + r0 + i;
    if (row >= n) continue;
    float res[8];
    #pragma unroll
    for (int j = 0; j < 8; ++j) {
      float v = acc[i][j] + b1[c0 + j];
      res[j] = 1.f / (1.f + __expf(-v));
    }
    if (left) {
      #pragma unroll
      for (int j = 0; j < 8; ++j)
        rh[(size_t)row * 128 + c0 + j] = res[j] * h[(size_t)row * 128 + c0 + j];
    } else {
      #pragma unroll
      for (int j = 0; j < 8; ++j) u[(size_t)row * 128 + (c0 - 128) + j] = res[j];
    }
  }
}

// c = tanh([f,rh] @ W2 + b2); out = u*h + (1-u)*c
__global__ __launch_bounds__(256) void gemm_out(const float* __restrict__ fbuf,
                                                const float* __restrict__ rh,
                                                const float* __restrict__ W2,
                                                const float* __restrict__ b2,
                                                const float* __restrict__ u,
                                                const float* __restrict__ h,
                                                float* __restrict__ out, int n) {
  __shared__ float Ws[64 * 128];   // 32 KB chunk of W2
  __shared__ float As[64 * 33];
  int row0 = blockIdx.x * 32;
  int t = threadIdx.x;
  int cg = t & 31, rg = t >> 5;
  int c0 = cg * 4, r0 = rg * 4;
  float acc[4][4] = {};
  for (int kc = 0; kc < 4; ++kc) {
    const float4* Wv = (const float4*)(W2 + (size_t)kc * 64 * 128);
    float4* Wsv = (float4*)Ws;
    #pragma unroll
    for (int rep = 0; rep < 8; ++rep) Wsv[t + rep * 256] = Wv[t + rep * 256];
    const float* __restrict__ srcp = (kc < 2) ? fbuf : rh;
    int cbase = (kc & 1) * 64;
    #pragma unroll
    for (int rep = 0; rep < 2; ++rep) {
      int idx = t + rep * 256;
      int r = idx >> 4, k4 = idx & 15;
      int row = row0 + r;
      float4 v = make_float4(0.f, 0.f, 0.f, 0.f);
      if (row < n) v = *(const float4*)(srcp + (size_t)row * 128 + cbase + k4 * 4);
      As[(k4 * 4 + 0) * 33 + r] = v.x;
      As[(k4 * 4 + 1) * 33 + r] = v.y;
      As[(k4 * 4 + 2) * 33 + r] = v.z;
      As[(k4 * 4 + 3) * 33 + r] = v.w;
    }
    __syncthreads();
    #pragma unroll 4
    for (int k = 0; k < 64; ++k) {
      float xv[4];
      #pragma unroll
      for (int i = 0; i < 4; ++i) xv[i] = As[k * 33 + r0 + i];
      float4 wa = *(const float4*)&Ws[k * 128 + c0];
      float wv[4] = {wa.x, wa.y, wa.z, wa.w};
      #pragma unroll
      for (int i = 0; i < 4; ++i)
        #pragma unroll
        for (int j = 0; j < 4; ++j) acc[i][j] = fmaf(xv[i], wv[j], acc[i][j]);
    }
    __syncthreads();
  }
  #pragma unroll
  for (int i = 0; i < 4; ++i) {
    int row = row0 + r0 + i;
    if (row >= n) continue;
    float4 uu = *(const float4*)(u + (size_t)row * 128 + c0);
    float4 hh = *(const float4*)(h + (size_t)row * 128 + c0);
    float cv[4];
    #pragma unroll
    for (int j = 0; j < 4; ++j) cv[j] = tanhf(acc[i][j] + b2[c0 + j]);
    float4 o;
    o.x = uu.x * hh.x + (1.f - uu.x) * cv[0];
    o.y = uu.y * hh.y + (1.f - uu.y) * cv[1];
    o.z = uu.z * hh.z + (1.f - uu.z) * cv[2];
    o.w = uu.w * hh.w + (1.f - uu.w) * cv[3];
    *(float4*)(out + (size_t)row * 128 + c0) = o;
  }
}

extern "C" void kernel_launch(void* const* d_in, const int* in_sizes, int n_in,
                              void* d_out, int out_size, void* d_ws, size_t ws_size,
                              hipStream_t stream) {
  const float* x     = (const float*)d_in[0];
  const void*  ei    = d_in[1];
  const float* h     = (const float*)d_in[3];
  const float* Wl    = (const float*)d_in[4];
  const float* Wr    = (const float*)d_in[5];
  const float* att   = (const float*)d_in[6];
  const float* bconv = (const float*)d_in[7];
  const float* W1    = (const float*)d_in[8];
  const float* b1    = (const float*)d_in[9];
  const float* W2    = (const float*)d_in[10];
  const float* b2    = (const float*)d_in[11];
  float* out = (float*)d_out;

  const int n = in_sizes[0] / 128;   // 50000
  const int E = in_sizes[1] / 2;     // 800000

  char* w = (char*)d_ws;
  size_t o = 0;
  auto alloc = [&](size_t bytes) {
    char* p = w + o;
    o += bytes;
    o = (o + 255) & ~(size_t)255;
    return p;
  };
  int* flag   = (int*)alloc(4);
  int* src32  = (int*)alloc((size_t)E * 4);
  int* dst32  = (int*)alloc((size_t)E * 4);
  int* deg    = (int*)alloc((size_t)(n + 1) * 4);
  int* off    = (int*)alloc((size_t)(n + 1) * 4);
  int* cursor = (int*)alloc((size_t)(n + 1) * 4);
  int* csr    = (int*)alloc((size_t)E * 4);
  float* xl   = (float*)alloc((size_t)n * 128 * 4);
  float* xr   = (float*)alloc((size_t)n * 128 * 4);
  float* fbuf = (float*)alloc((size_t)n * 128 * 4);
  float* rh = xl;   // xl/xr dead after node pass -> reuse
  float* u  = xr;

  hipMemsetAsync(deg, 0, (size_t)(n + 1) * 4, stream);
  detect_kernel<<<1, 1024, 0, stream>>>((const unsigned int*)ei, 2LL * E, flag);
  convert_kernel<<<(E + 255) / 256, 256, 0, stream>>>(ei, E, flag, src32, dst32);
  hist_kernel<<<(E + 255) / 256, 256, 0, stream>>>(dst32, deg, E);
  scan_kernel<<<1, 1024, 0, stream>>>(deg, off, cursor, n);
  scatter_kernel<<<(E + 255) / 256, 256, 0, stream>>>(src32, dst32, cursor, csr, E);
  gemm_xw<<<dim3((n + 31) / 32, 2), 256, 0, stream>>>(x, Wl, Wr, xl, xr, n);
  node_kernel<<<(n + 3) / 4, 256, 0, stream>>>(xl, xr, att, bconv, off, csr, fbuf, n);
  gemm_ru<<<(n + 31) / 32, 256, 0, stream>>>(fbuf, h, W1, b1, rh, u, n);
  gemm_out<<<(n + 31) / 32, 256, 0, stream>>>(fbuf, rh, W2, b2, u, h, out, n);
}

// Round 2
// 386.358 us; speedup vs baseline: 1.4203x; 1.4203x over previous
//
#include <hip/hip_runtime.h>
#include <hip/hip_bf16.h>
#include <math.h>

typedef __attribute__((ext_vector_type(8))) short short8;
typedef __attribute__((ext_vector_type(4))) float floatx4;

__device__ __forceinline__ unsigned short f2b(float f) {
  unsigned int u = __builtin_bit_cast(unsigned int, f);
  u += 0x7fffu + ((u >> 16) & 1u);
  return (unsigned short)(u >> 16);
}
__device__ __forceinline__ float b2f(unsigned short s) {
  unsigned int u = ((unsigned int)s) << 16;
  return __builtin_bit_cast(float, u);
}

// ---------------------------------------------------------------------------
// Edge preprocessing
// ---------------------------------------------------------------------------
__global__ __launch_bounds__(1024) void detect_kernel(const unsigned int* __restrict__ ei,
                                                      long long n_u32, int* __restrict__ flag) {
  __shared__ int any;
  if (threadIdx.x == 0) any = 0;
  __syncthreads();
  int nz = 0;
  for (int rep = 0; rep < 4; ++rep) {
    long long idx = 2LL * (threadIdx.x + rep * 1024) + 1;  // odd u32 slots
    if (idx < n_u32 && ei[idx] != 0u) nz = 1;
  }
  if (nz) atomicOr(&any, 1);
  __syncthreads();
  if (threadIdx.x == 0) *flag = any;  // 1 -> int32 data, 0 -> int64 data
}

// convert edge_index -> src32/dst32 AND histogram in-degree (fused)
__global__ __launch_bounds__(256) void convert_hist(const void* __restrict__ ei, int E,
                                                    const int* __restrict__ flag,
                                                    int* __restrict__ src32,
                                                    int* __restrict__ dst32,
                                                    int* __restrict__ deg) {
  int i = blockIdx.x * 256 + threadIdx.x;
  if (i >= E) return;
  int s, d;
  if (*flag == 0) {  // int64
    const long long* p = (const long long*)ei;
    s = (int)p[i];
    d = (int)p[(long long)E + i];
  } else {           // int32
    const int* p = (const int*)ei;
    s = p[i];
    d = p[E + i];
  }
  src32[i] = s;
  dst32[i] = d;
  atomicAdd(&deg[d], 1);
}

// single-block exclusive scan of deg[0..n-1] -> off[0..n], cursor copy
__global__ __launch_bounds__(1024) void scan_kernel(const int* __restrict__ deg,
                                                    int* __restrict__ off,
                                                    int* __restrict__ cursor, int n) {
  __shared__ int wsum[16];
  int lane = threadIdx.x & 63, wid = threadIdx.x >> 6;
  if (threadIdx.x == 0) { off[0] = 0; cursor[0] = 0; }
  int carry = 0;
  for (int base = 0; base < n; base += 1024) {
    int i = base + (int)threadIdx.x;
    int v = (i < n) ? deg[i] : 0;
    int s = v;
    #pragma unroll
    for (int ofs = 1; ofs < 64; ofs <<= 1) {
      int t = __shfl_up(s, ofs, 64);
      if (lane >= ofs) s += t;
    }
    if (lane == 63) wsum[wid] = s;
    __syncthreads();
    int wpre = 0;
    for (int ww = 0; ww < wid; ++ww) wpre += wsum[ww];
    int incl = s + wpre + carry;
    if (i < n) { off[i + 1] = incl; cursor[i + 1] = incl; }
    int total = 0;
    for (int ww = 0; ww < 16; ++ww) total += wsum[ww];
    carry += total;
    __syncthreads();
  }
}

__global__ __launch_bounds__(256) void scatter_kernel(const int* __restrict__ src32,
                                                      const int* __restrict__ dst32,
                                                      int* __restrict__ cursor,
                                                      int* __restrict__ csr, int E) {
  int i = blockIdx.x * 256 + threadIdx.x;
  if (i >= E) return;
  int pos = atomicAdd(&cursor[dst32[i]], 1);
  csr[pos] = src32[i];
}

// ---------------------------------------------------------------------------
// One-time conversions: x,h -> bf16; weights -> transposed bf16 (B^T [N][K])
// ---------------------------------------------------------------------------
__global__ __launch_bounds__(256) void cvt_xh(const float* __restrict__ x,
                                              const float* __restrict__ h,
                                              unsigned short* __restrict__ xb,
                                              unsigned short* __restrict__ hb,
                                              long long total4) {
  long long i = blockIdx.x * 256LL + threadIdx.x;
  if (i >= total4) return;
  const float* src = blockIdx.y ? h : x;
  unsigned short* dst = blockIdx.y ? hb : xb;
  float4 v = *(const float4*)(src + i * 4);
  ushort4 o;
  o.x = f2b(v.x); o.y = f2b(v.y); o.z = f2b(v.z); o.w = f2b(v.w);
  *(ushort4*)(dst + i * 4) = o;
}

__global__ __launch_bounds__(256) void wprep(const float* __restrict__ Wl,
                                             const float* __restrict__ Wr,
                                             const float* __restrict__ W1,
                                             const float* __restrict__ W2,
                                             unsigned short* __restrict__ Btxw,
                                             unsigned short* __restrict__ Bt1,
                                             unsigned short* __restrict__ Bt2) {
  int idx = blockIdx.x * 256 + threadIdx.x;  // 131072 total
  if (idx < 32768) {                         // Btxw[256][128]: [Wl^T; Wr^T]
    int nn = idx >> 7, k = idx & 127;
    float v = (nn < 128) ? Wl[k * 128 + nn] : Wr[k * 128 + (nn - 128)];
    Btxw[nn * 128 + k] = f2b(v);
  } else if (idx < 98304) {                  // Bt1[256][256] = W1^T
    int loc = idx - 32768;
    int nn = loc >> 8, k = loc & 255;
    Bt1[nn * 256 + k] = f2b(W1[k * 256 + nn]);
  } else {                                   // Bt2[128][256] = W2^T
    int loc = idx - 98304;
    int nn = loc >> 8, k = loc & 255;
    Bt2[nn * 256 + k] = f2b(W2[k * 128 + nn]);
  }
}

// ---------------------------------------------------------------------------
// MFMA GEMM template: C[M x NDIM] = A[M x KDIM] * B[KDIM x NDIM] (+epilogue)
// A given as one or two 128-col bf16 row-major sources; B given as bf16 B^T.
// Block = 256 thr = 4 waves (2x2); block tile 64 x NDIM; wave 32 x NDIM/2.
// LDS tiles XOR-swizzled (byte ^= (row&7)<<4) for conflict-free ds_read_b128.
// EPI 0: out cols<128 -> o0 (bf16), cols>=128 -> o1 (bf16)          [xl|xr]
// EPI 1: s=sigmoid(acc+bias); col<128: o0=s*b2f(p0) ; else o1=s     [rh|u]
// EPI 2: c=tanh(acc+bias); of = b2f(p0)*p1 + (1-b2f(p0))*c          [final]
// ---------------------------------------------------------------------------
template <int KDIM, int NDIM, int EPI>
__global__ __launch_bounds__(256) void gemm_mfma(const unsigned short* __restrict__ A0,
                                                 const unsigned short* __restrict__ A1,
                                                 const unsigned short* __restrict__ Bt,
                                                 const float* __restrict__ bias,
                                                 const unsigned short* __restrict__ p0,
                                                 const float* __restrict__ p1,
                                                 unsigned short* __restrict__ o0,
                                                 unsigned short* __restrict__ o1,
                                                 float* __restrict__ of, int n) {
  constexpr int NT = NDIM / 32;        // col tiles per wave
  constexpr int NSTEP = KDIM / 64;
  __shared__ char smem[64 * 128 + NDIM * 128];
  char* Abase = smem;                  // A tile: 64 rows x 128 B
  char* Bbase = smem + 64 * 128;       // Bt tile: NDIM rows x 128 B

  int t = threadIdx.x;
  int w = t >> 6, l = t & 63;
  int wm = w >> 1, wn = w & 1;
  int row0 = blockIdx.x * 64;
  int l15 = l & 15, lhi = l >> 4;

  floatx4 acc[2][NT];
  #pragma unroll
  for (int mt = 0; mt < 2; ++mt)
    #pragma unroll
    for (int nt = 0; nt < NT; ++nt) acc[mt][nt] = (floatx4){0.f, 0.f, 0.f, 0.f};

  for (int ks = 0; ks < NSTEP; ++ks) {
    // stage A chunk (cols ks*64 .. +64)
    const unsigned short* Asrc = (KDIM == 256) ? (ks >= 2 ? A1 : A0) : A0;
    int kbase = (KDIM == 256) ? ((ks & 1) * 64) : (ks * 64);
    #pragma unroll
    for (int u_ = 0; u_ < 2; ++u_) {
      int unit = t + u_ * 256;         // 512 x 16B
      int r = unit >> 3, b16 = unit & 7;
      int grow = row0 + r;
      uint4 v = make_uint4(0, 0, 0, 0);
      if (grow < n) v = *(const uint4*)(Asrc + (size_t)grow * 128 + kbase + b16 * 8);
      *(uint4*)(Abase + r * 128 + ((b16 * 16) ^ ((r & 7) << 4))) = v;
    }
    // stage Bt chunk (cols ks*64 .. +64)
    #pragma unroll
    for (int u_ = 0; u_ < NDIM * 8 / 256; ++u_) {
      int unit = t + u_ * 256;
      int r = unit >> 3, b16 = unit & 7;
      uint4 v = *(const uint4*)(Bt + (size_t)r * KDIM + ks * 64 + b16 * 8);
      *(uint4*)(Bbase + r * 128 + ((b16 * 16) ^ ((r & 7) << 4))) = v;
    }
    __syncthreads();
    #pragma unroll
    for (int kk = 0; kk < 2; ++kk) {   // two K=32 slices
      int koff = kk * 64 + lhi * 16;   // byte offset of this lane's 8 bf16
      short8 a[2];
      #pragma unroll
      for (int mt = 0; mt < 2; ++mt) {
        int r = wm * 32 + mt * 16 + l15;
        a[mt] = *(const short8*)(Abase + r * 128 + (koff ^ ((r & 7) << 4)));
      }
      #pragma unroll
      for (int nt = 0; nt < NT; ++nt) {
        int r = wn * (NDIM / 2) + nt * 16 + l15;
        short8 b = *(const short8*)(Bbase + r * 128 + (koff ^ ((r & 7) << 4)));
        acc[0][nt] = __builtin_amdgcn_mfma_f32_16x16x32_bf16(a[0], b, acc[0][nt], 0, 0, 0);
        acc[1][nt] = __builtin_amdgcn_mfma_f32_16x16x32_bf16(a[1], b, acc[1][nt], 0, 0, 0);
      }
    }
    __syncthreads();
  }

  // epilogue: D layout col = l&15, row = 4*(l>>4)+j
  #pragma unroll
  for (int mt = 0; mt < 2; ++mt) {
    #pragma unroll
    for (int nt = 0; nt < NT; ++nt) {
      int col = wn * (NDIM / 2) + nt * 16 + l15;
      int rbase = row0 + wm * 32 + mt * 16 + lhi * 4;
      #pragma unroll
      for (int j = 0; j < 4; ++j) {
        int row = rbase + j;
        if (row >= n) continue;
        float v = acc[mt][nt][j];
        if (EPI == 0) {
          if (col < 128) o0[(size_t)row * 128 + col] = f2b(v);
          else           o1[(size_t)row * 128 + (col - 128)] = f2b(v);
        } else if (EPI == 1) {
          float s = 1.f / (1.f + __expf(-(v + bias[col])));
          if (col < 128) o0[(size_t)row * 128 + col] = f2b(s * b2f(p0[(size_t)row * 128 + col]));
          else           o1[(size_t)row * 128 + (col - 128)] = f2b(s);
        } else {
          float c = tanhf(v + bias[col]);
          float uu = b2f(p0[(size_t)row * 128 + col]);
          float hv = p1[(size_t)row * 128 + col];
          of[(size_t)row * 128 + col] = uu * hv + (1.f - uu) * c;
        }
      }
    }
  }
}

// ---------------------------------------------------------------------------
// One wave per node: softmax over in-edges + weighted aggregation (bf16 I/O)
// ---------------------------------------------------------------------------
__global__ __launch_bounds__(256) void node_kernel(const unsigned short* __restrict__ xl,
                                                   const unsigned short* __restrict__ xr,
                                                   const float* __restrict__ att,
                                                   const float* __restrict__ bias,
                                                   const int* __restrict__ off,
                                                   const int* __restrict__ csr,
                                                   unsigned short* __restrict__ f, int n) {
  int wid = threadIdx.x >> 6, lane = threadIdx.x & 63;
  int node = blockIdx.x * 4 + wid;
  if (node >= n) return;
  int c0 = lane, c1 = lane + 64;
  float a0 = att[c0], a1 = att[c1];
  float xr0 = b2f(xr[(size_t)node * 128 + c0]);
  float xr1 = b2f(xr[(size_t)node * 128 + c1]);
  float num0 = 0.f, num1 = 0.f, den0 = 0.f, den1 = 0.f;
  int beg = off[node], end = off[node + 1];
  for (int j = beg - 1; j < end; ++j) {   // j == beg-1 encodes the self loop
    int src = (j < beg) ? node : csr[j];
    float xls0 = b2f(xl[(size_t)src * 128 + c0]);
    float xls1 = b2f(xl[(size_t)src * 128 + c1]);
    float m0 = xls0 + xr0, m1 = xls1 + xr1;
    float l0 = m0 > 0.f ? m0 : 0.2f * m0;
    float l1 = m1 > 0.f ? m1 : 0.2f * m1;
    float p0 = l0 * a0, p1 = l1 * a1;
    #pragma unroll
    for (int mask = 1; mask < 32; mask <<= 1) {   // per-head (32-lane) reduce
      p0 += __shfl_xor(p0, mask, 64);
      p1 += __shfl_xor(p1, mask, 64);
    }
    float w0 = __expf(p0), w1 = __expf(p1);   // no max-subtract: same softmax
    num0 = fmaf(w0, xls0, num0);
    num1 = fmaf(w1, xls1, num1);
    den0 += w0;
    den1 += w1;
  }
  float v0 = num0 / (den0 + 1e-16f) + bias[c0];
  float v1 = num1 / (den1 + 1e-16f) + bias[c1];
  f[(size_t)node * 128 + c0] = f2b(1.f / (1.f + __expf(-v0)));
  f[(size_t)node * 128 + c1] = f2b(1.f / (1.f + __expf(-v1)));
}

extern "C" void kernel_launch(void* const* d_in, const int* in_sizes, int n_in,
                              void* d_out, int out_size, void* d_ws, size_t ws_size,
                              hipStream_t stream) {
  const float* x     = (const float*)d_in[0];
  const void*  ei    = d_in[1];
  const float* h     = (const float*)d_in[3];
  const float* Wl    = (const float*)d_in[4];
  const float* Wr    = (const float*)d_in[5];
  const float* att   = (const float*)d_in[6];
  const float* bconv = (const float*)d_in[7];
  const float* W1    = (const float*)d_in[8];
  const float* b1    = (const float*)d_in[9];
  const float* W2    = (const float*)d_in[10];
  const float* b2    = (const float*)d_in[11];
  float* out = (float*)d_out;

  const int n = in_sizes[0] / 128;   // 50000
  const int E = in_sizes[1] / 2;     // 800000

  char* w = (char*)d_ws;
  size_t o = 0;
  auto alloc = [&](size_t bytes) {
    char* p = w + o;
    o += bytes;
    o = (o + 255) & ~(size_t)255;
    return p;
  };
  int* flag   = (int*)alloc(4);
  int* src32  = (int*)alloc((size_t)E * 4);
  int* dst32  = (int*)alloc((size_t)E * 4);
  int* deg    = (int*)alloc((size_t)(n + 1) * 4);
  int* off    = (int*)alloc((size_t)(n + 1) * 4);
  int* cursor = (int*)alloc((size_t)(n + 1) * 4);
  int* csr    = (int*)alloc((size_t)E * 4);
  unsigned short* xb   = (unsigned short*)alloc((size_t)n * 128 * 2);
  unsigned short* hb   = (unsigned short*)alloc((size_t)n * 128 * 2);
  unsigned short* xl   = (unsigned short*)alloc((size_t)n * 128 * 2);
  unsigned short* xr   = (unsigned short*)alloc((size_t)n * 128 * 2);
  unsigned short* fbuf = (unsigned short*)alloc((size_t)n * 128 * 2);
  unsigned short* Btxw = (unsigned short*)alloc(256 * 128 * 2);
  unsigned short* Bt1  = (unsigned short*)alloc(256 * 256 * 2);
  unsigned short* Bt2  = (unsigned short*)alloc(128 * 256 * 2);
  unsigned short* rh = xl;   // xl/xr dead after node pass -> reuse
  unsigned short* u  = xr;

  hipMemsetAsync(deg, 0, (size_t)(n + 1) * 4, stream);
  detect_kernel<<<1, 1024, 0, stream>>>((const unsigned int*)ei, 2LL * E, flag);
  convert_hist<<<(E + 255) / 256, 256, 0, stream>>>(ei, E, flag, src32, dst32, deg);
  scan_kernel<<<1, 1024, 0, stream>>>(deg, off, cursor, n);
  scatter_kernel<<<(E + 255) / 256, 256, 0, stream>>>(src32, dst32, cursor, csr, E);
  long long total4 = (long long)n * 128 / 4;
  cvt_xh<<<dim3((unsigned)((total4 + 255) / 256), 2), 256, 0, stream>>>(x, h, xb, hb, total4);
  wprep<<<512, 256, 0, stream>>>(Wl, Wr, W1, W2, Btxw, Bt1, Bt2);

  int gblocks = (n + 63) / 64;
  gemm_mfma<128, 256, 0><<<gblocks, 256, 0, stream>>>(xb, nullptr, Btxw, nullptr,
                                                      nullptr, nullptr, xl, xr, nullptr, n);
  node_kernel<<<(n + 3) / 4, 256, 0, stream>>>(xl, xr, att, bconv, off, csr, fbuf, n);
  gemm_mfma<256, 256, 1><<<gblocks, 256, 0, stream>>>(fbuf, hb, Bt1, b1,
                                                      hb, nullptr, rh, u, nullptr, n);
  gemm_mfma<256, 128, 2><<<gblocks, 256, 0, stream>>>(fbuf, rh, Bt2, b2,
                                                      u, h, nullptr, nullptr, out, n);
}

// Round 3
// 297.197 us; speedup vs baseline: 1.8464x; 1.3000x over previous
//
#include <hip/hip_runtime.h>
#include <hip/hip_bf16.h>
#include <math.h>

typedef __attribute__((ext_vector_type(8))) short short8;
typedef __attribute__((ext_vector_type(4))) float floatx4;

__device__ __forceinline__ unsigned short f2b(float f) {
  unsigned int u = __builtin_bit_cast(unsigned int, f);
  u += 0x7fffu + ((u >> 16) & 1u);
  return (unsigned short)(u >> 16);
}
__device__ __forceinline__ float b2f(unsigned short s) {
  unsigned int u = ((unsigned int)s) << 16;
  return __builtin_bit_cast(float, u);
}

// ---------------------------------------------------------------------------
// Edge preprocessing
// ---------------------------------------------------------------------------
__global__ __launch_bounds__(1024) void detect_kernel(const unsigned int* __restrict__ ei,
                                                      long long n_u32, int* __restrict__ flag) {
  __shared__ int any;
  if (threadIdx.x == 0) any = 0;
  __syncthreads();
  int nz = 0;
  for (int rep = 0; rep < 4; ++rep) {
    long long idx = 2LL * (threadIdx.x + rep * 1024) + 1;  // odd u32 slots
    if (idx < n_u32 && ei[idx] != 0u) nz = 1;
  }
  if (nz) atomicOr(&any, 1);
  __syncthreads();
  if (threadIdx.x == 0) *flag = any;  // 1 -> int32 data, 0 -> int64 data
}

__global__ __launch_bounds__(256) void convert_hist(const void* __restrict__ ei, int E,
                                                    const int* __restrict__ flag,
                                                    int* __restrict__ src32,
                                                    int* __restrict__ dst32,
                                                    int* __restrict__ deg) {
  int i = blockIdx.x * 256 + threadIdx.x;
  if (i >= E) return;
  int s, d;
  if (*flag == 0) {
    const long long* p = (const long long*)ei;
    s = (int)p[i];
    d = (int)p[(long long)E + i];
  } else {
    const int* p = (const int*)ei;
    s = p[i];
    d = p[E + i];
  }
  src32[i] = s;
  dst32[i] = d;
  atomicAdd(&deg[d], 1);
}

__global__ __launch_bounds__(1024) void scan_kernel(const int* __restrict__ deg,
                                                    int* __restrict__ off,
                                                    int* __restrict__ cursor, int n) {
  __shared__ int wsum[16];
  int lane = threadIdx.x & 63, wid = threadIdx.x >> 6;
  if (threadIdx.x == 0) { off[0] = 0; cursor[0] = 0; }
  int carry = 0;
  for (int base = 0; base < n; base += 1024) {
    int i = base + (int)threadIdx.x;
    int v = (i < n) ? deg[i] : 0;
    int s = v;
    #pragma unroll
    for (int ofs = 1; ofs < 64; ofs <<= 1) {
      int t = __shfl_up(s, ofs, 64);
      if (lane >= ofs) s += t;
    }
    if (lane == 63) wsum[wid] = s;
    __syncthreads();
    int wpre = 0;
    for (int ww = 0; ww < wid; ++ww) wpre += wsum[ww];
    int incl = s + wpre + carry;
    if (i < n) { off[i + 1] = incl; cursor[i + 1] = incl; }
    int total = 0;
    for (int ww = 0; ww < 16; ++ww) total += wsum[ww];
    carry += total;
    __syncthreads();
  }
}

__global__ __launch_bounds__(256) void scatter_kernel(const int* __restrict__ src32,
                                                      const int* __restrict__ dst32,
                                                      int* __restrict__ cursor,
                                                      int* __restrict__ csr, int E) {
  int i = blockIdx.x * 256 + threadIdx.x;
  if (i >= E) return;
  int pos = atomicAdd(&cursor[dst32[i]], 1);
  csr[pos] = src32[i];
}

// weights -> transposed bf16 (B^T [N][K])
__global__ __launch_bounds__(256) void wprep(const float* __restrict__ Wl,
                                             const float* __restrict__ Wr,
                                             const float* __restrict__ W1,
                                             const float* __restrict__ W2,
                                             unsigned short* __restrict__ Btxw,
                                             unsigned short* __restrict__ Bt1,
                                             unsigned short* __restrict__ Bt2) {
  int idx = blockIdx.x * 256 + threadIdx.x;  // 131072 total
  if (idx < 32768) {                         // Btxw[256][128]: [Wl^T; Wr^T]
    int nn = idx >> 7, k = idx & 127;
    float v = (nn < 128) ? Wl[k * 128 + nn] : Wr[k * 128 + (nn - 128)];
    Btxw[nn * 128 + k] = f2b(v);
  } else if (idx < 98304) {                  // Bt1[256][256] = W1^T
    int loc = idx - 32768;
    int nn = loc >> 8, k = loc & 255;
    Bt1[nn * 256 + k] = f2b(W1[k * 256 + nn]);
  } else {                                   // Bt2[128][256] = W2^T
    int loc = idx - 98304;
    int nn = loc >> 8, k = loc & 255;
    Bt2[nn * 256 + k] = f2b(W2[k * 128 + nn]);
  }
}

// ---------------------------------------------------------------------------
// xl|xr = x @ [Wl|Wr]   (A = f32 x, converted during staging)
// Block 64 rows, 4 waves 2x2; wave = 32 rows x 128 cols (NT=8).
// ---------------------------------------------------------------------------
__global__ __launch_bounds__(256) void gemm_xw(const float* __restrict__ x,
                                               const unsigned short* __restrict__ Bt,
                                               unsigned short* __restrict__ xl,
                                               unsigned short* __restrict__ xr, int n) {
  __shared__ char As[64 * 256];    // 64 rows x 128 bf16 (full K), swizzled
  __shared__ char Bs[256 * 128];   // 256 N-rows x 64 K bf16 chunk, swizzled
  int t = threadIdx.x;
  int w = t >> 6, l = t & 63;
  int wm = w >> 1, wn = w & 1;
  int row0 = blockIdx.x * 64;
  int l15 = l & 15, lhi = l >> 4;

  // stage A from f32 (1024 units of 16B = 8 bf16 <- 8 f32)
  #pragma unroll
  for (int u_ = 0; u_ < 4; ++u_) {
    int unit = t + u_ * 256;
    int r = unit >> 4, slot = unit & 15;
    int grow = row0 + r;
    uint4 o = make_uint4(0, 0, 0, 0);
    if (grow < n) {
      const float* s = x + (size_t)grow * 128 + slot * 8;
      float4 f0 = *(const float4*)s, f1 = *(const float4*)(s + 4);
      o.x = (unsigned)f2b(f0.x) | ((unsigned)f2b(f0.y) << 16);
      o.y = (unsigned)f2b(f0.z) | ((unsigned)f2b(f0.w) << 16);
      o.z = (unsigned)f2b(f1.x) | ((unsigned)f2b(f1.y) << 16);
      o.w = (unsigned)f2b(f1.z) | ((unsigned)f2b(f1.w) << 16);
    }
    *(uint4*)(As + r * 256 + ((slot * 16) ^ ((r & 7) << 4))) = o;
  }

  floatx4 acc[2][8];
  #pragma unroll
  for (int mt = 0; mt < 2; ++mt)
    #pragma unroll
    for (int nt = 0; nt < 8; ++nt) acc[mt][nt] = (floatx4){0.f, 0.f, 0.f, 0.f};

  for (int ks = 0; ks < 2; ++ks) {
    #pragma unroll
    for (int u_ = 0; u_ < 8; ++u_) {
      int unit = t + u_ * 256;
      int r = unit >> 3, b16 = unit & 7;
      uint4 v = *(const uint4*)(Bt + (size_t)r * 128 + ks * 64 + b16 * 8);
      *(uint4*)(Bs + r * 128 + ((b16 * 16) ^ ((r & 7) << 4))) = v;
    }
    __syncthreads();
    #pragma unroll
    for (int kk = 0; kk < 2; ++kk) {
      int ka = ks * 128 + kk * 64 + lhi * 16;
      short8 a[2];
      #pragma unroll
      for (int mt = 0; mt < 2; ++mt) {
        int r = wm * 32 + mt * 16 + l15;
        a[mt] = *(const short8*)(As + r * 256 + (ka ^ ((r & 7) << 4)));
      }
      int kb = kk * 64 + lhi * 16;
      #pragma unroll
      for (int nt = 0; nt < 8; ++nt) {
        int r = wn * 128 + nt * 16 + l15;
        short8 b = *(const short8*)(Bs + r * 128 + (kb ^ ((r & 7) << 4)));
        acc[0][nt] = __builtin_amdgcn_mfma_f32_16x16x32_bf16(a[0], b, acc[0][nt], 0, 0, 0);
        acc[1][nt] = __builtin_amdgcn_mfma_f32_16x16x32_bf16(a[1], b, acc[1][nt], 0, 0, 0);
      }
    }
    __syncthreads();
  }

  #pragma unroll
  for (int mt = 0; mt < 2; ++mt)
    #pragma unroll
    for (int nt = 0; nt < 8; ++nt) {
      int col = wn * 128 + nt * 16 + l15;
      int rbase = row0 + wm * 32 + mt * 16 + lhi * 4;
      #pragma unroll
      for (int j = 0; j < 4; ++j) {
        int row = rbase + j;
        if (row >= n) continue;
        unsigned short v = f2b(acc[mt][nt][j]);
        if (col < 128) xl[(size_t)row * 128 + col] = v;
        else           xr[(size_t)row * 128 + (col - 128)] = v;
      }
    }
}

// ---------------------------------------------------------------------------
// One wave per node. Lane l owns dims (2l, 2l+1); head = l>>4.
// Per edge: 1 coalesced u32 gather, 4 shfl (16-lane reduce), 1 exp.
// CSR indices batch-loaded (64/load) and broadcast via readlane.
// ---------------------------------------------------------------------------
__global__ __launch_bounds__(256) void node_kernel(const unsigned int* __restrict__ xl32,
                                                   const unsigned int* __restrict__ xr32,
                                                   const float* __restrict__ att,
                                                   const float* __restrict__ bias,
                                                   const int* __restrict__ off,
                                                   const int* __restrict__ csr,
                                                   unsigned int* __restrict__ fout, int n) {
  int wid = threadIdx.x >> 6, lane = threadIdx.x & 63;
  int node = blockIdx.x * 4 + wid;
  if (node >= n) return;
  float a0 = att[2 * lane], a1 = att[2 * lane + 1];
  unsigned int xrp = xr32[(size_t)node * 64 + lane];
  float xr0 = b2f((unsigned short)xrp);
  float xr1 = b2f((unsigned short)(xrp >> 16));
  float num0 = 0.f, num1 = 0.f, den = 0.f;
  int beg = off[node], end = off[node + 1];

  auto edge = [&](int src) {
    unsigned int g = xl32[(size_t)src * 64 + lane];
    float x0 = b2f((unsigned short)g), x1 = b2f((unsigned short)(g >> 16));
    float m0 = x0 + xr0, m1 = x1 + xr1;
    float l0 = fmaxf(m0, 0.2f * m0), l1 = fmaxf(m1, 0.2f * m1);  // leaky relu
    float p = fmaf(l1, a1, l0 * a0);
    #pragma unroll
    for (int mask = 1; mask < 16; mask <<= 1) p += __shfl_xor(p, mask, 64);
    float wgt = __expf(p);   // no max-subtract: identical softmax
    num0 = fmaf(wgt, x0, num0);
    num1 = fmaf(wgt, x1, num1);
    den += wgt;
  };

  edge(node);  // self loop
  for (int base = beg; base < end; base += 64) {
    int cnt = end - base;
    if (cnt > 64) cnt = 64;
    int my = csr[base + (lane < cnt ? lane : 0)];
    int i = 0;
    for (; i + 2 <= cnt; i += 2) {
      int s0 = __builtin_amdgcn_readlane(my, i);
      int s1 = __builtin_amdgcn_readlane(my, i + 1);
      edge(s0);
      edge(s1);
    }
    if (i < cnt) edge(__builtin_amdgcn_readlane(my, i));
  }
  float inv = 1.f / (den + 1e-16f);
  float v0 = num0 * inv + bias[2 * lane];
  float v1 = num1 * inv + bias[2 * lane + 1];
  float s0 = 1.f / (1.f + __expf(-v0));
  float s1 = 1.f / (1.f + __expf(-v1));
  fout[(size_t)node * 64 + lane] = (unsigned)f2b(s0) | ((unsigned)f2b(s1) << 16);
}

// ---------------------------------------------------------------------------
// Fused GRU GEMMs:
//   phase1: acc = [f|h] @ W1^T; r-cols -> rh written over h in LDS; u -> Us
//   phase2: acc2 = [f|rh] @ W2^T; out = u*h + (1-u)*tanh(acc2+b2)
// ---------------------------------------------------------------------------
__global__ __launch_bounds__(256) void gemm_fused(const unsigned short* __restrict__ fbuf,
                                                  const float* __restrict__ hf,
                                                  const unsigned short* __restrict__ Bt1,
                                                  const unsigned short* __restrict__ Bt2,
                                                  const float* __restrict__ b1,
                                                  const float* __restrict__ b2,
                                                  float* __restrict__ out, int n) {
  __shared__ char As[64 * 512];           // [f|h] 64 rows x 256 bf16, swizzled
  __shared__ char Bs[256 * 128];          // B chunk, swizzled
  __shared__ unsigned short Us[64 * 128]; // u gate (bf16)
  int t = threadIdx.x;
  int w = t >> 6, l = t & 63;
  int wm = w >> 1, wn = w & 1;
  int row0 = blockIdx.x * 64;
  int l15 = l & 15, lhi = l >> 4;

  // stage A = [f | h]: 2048 units of 16B; h converted from f32
  #pragma unroll
  for (int u_ = 0; u_ < 8; ++u_) {
    int unit = t + u_ * 256;
    int r = unit >> 5, slot = unit & 31;
    int koff = slot * 16;
    int grow = row0 + r;
    uint4 v = make_uint4(0, 0, 0, 0);
    if (grow < n) {
      if (koff < 256) {
        v = *(const uint4*)(fbuf + (size_t)grow * 128 + koff / 2);
      } else {
        const float* s = hf + (size_t)grow * 128 + (koff - 256) / 2;
        float4 f0 = *(const float4*)s, f1 = *(const float4*)(s + 4);
        v.x = (unsigned)f2b(f0.x) | ((unsigned)f2b(f0.y) << 16);
        v.y = (unsigned)f2b(f0.z) | ((unsigned)f2b(f0.w) << 16);
        v.z = (unsigned)f2b(f1.x) | ((unsigned)f2b(f1.y) << 16);
        v.w = (unsigned)f2b(f1.z) | ((unsigned)f2b(f1.w) << 16);
      }
    }
    *(uint4*)(As + r * 512 + (koff ^ ((r & 7) << 4))) = v;
  }

  // ---- phase 1: K=256, N=256 ----
  floatx4 acc[2][8];
  #pragma unroll
  for (int mt = 0; mt < 2; ++mt)
    #pragma unroll
    for (int nt = 0; nt < 8; ++nt) acc[mt][nt] = (floatx4){0.f, 0.f, 0.f, 0.f};

  for (int ks = 0; ks < 4; ++ks) {
    #pragma unroll
    for (int u_ = 0; u_ < 8; ++u_) {
      int unit = t + u_ * 256;
      int r = unit >> 3, b16 = unit & 7;
      uint4 v = *(const uint4*)(Bt1 + (size_t)r * 256 + ks * 64 + b16 * 8);
      *(uint4*)(Bs + r * 128 + ((b16 * 16) ^ ((r & 7) << 4))) = v;
    }
    __syncthreads();
    #pragma unroll
    for (int kk = 0; kk < 2; ++kk) {
      int ka = ks * 128 + kk * 64 + lhi * 16;
      short8 a[2];
      #pragma unroll
      for (int mt = 0; mt < 2; ++mt) {
        int r = wm * 32 + mt * 16 + l15;
        a[mt] = *(const short8*)(As + r * 512 + (ka ^ ((r & 7) << 4)));
      }
      int kb = kk * 64 + lhi * 16;
      #pragma unroll
      for (int nt = 0; nt < 8; ++nt) {
        int r = wn * 128 + nt * 16 + l15;
        short8 b = *(const short8*)(Bs + r * 128 + (kb ^ ((r & 7) << 4)));
        acc[0][nt] = __builtin_amdgcn_mfma_f32_16x16x32_bf16(a[0], b, acc[0][nt], 0, 0, 0);
        acc[1][nt] = __builtin_amdgcn_mfma_f32_16x16x32_bf16(a[1], b, acc[1][nt], 0, 0, 0);
      }
    }
    __syncthreads();
  }

  // phase-1 epilogue: r -> rh (overwrite h in LDS), u -> Us
  #pragma unroll
  for (int mt = 0; mt < 2; ++mt)
    #pragma unroll
    for (int nt = 0; nt < 8; ++nt) {
      int col = wn * 128 + nt * 16 + l15;
      #pragma unroll
      for (int j = 0; j < 4; ++j) {
        int rloc = wm * 32 + mt * 16 + lhi * 4 + j;
        float s = 1.f / (1.f + __expf(-(acc[mt][nt][j] + b1[col])));
        if (col < 128) {
          int byteoff = 256 + col * 2;
          char* p = As + rloc * 512 + (byteoff ^ ((rloc & 7) << 4));
          unsigned short hv = *(unsigned short*)p;
          *(unsigned short*)p = f2b(s * b2f(hv));
        } else {
          Us[rloc * 128 + (col - 128)] = f2b(s);
        }
      }
    }
  __syncthreads();

  // ---- phase 2: K=256, N=128 ----
  floatx4 acc2[2][4];
  #pragma unroll
  for (int mt = 0; mt < 2; ++mt)
    #pragma unroll
    for (int nt = 0; nt < 4; ++nt) acc2[mt][nt] = (floatx4){0.f, 0.f, 0.f, 0.f};

  for (int ks = 0; ks < 4; ++ks) {
    #pragma unroll
    for (int u_ = 0; u_ < 4; ++u_) {
      int unit = t + u_ * 256;
      int r = unit >> 3, b16 = unit & 7;
      uint4 v = *(const uint4*)(Bt2 + (size_t)r * 256 + ks * 64 + b16 * 8);
      *(uint4*)(Bs + r * 128 + ((b16 * 16) ^ ((r & 7) << 4))) = v;
    }
    __syncthreads();
    #pragma unroll
    for (int kk = 0; kk < 2; ++kk) {
      int ka = ks * 128 + kk * 64 + lhi * 16;
      short8 a[2];
      #pragma unroll
      for (int mt = 0; mt < 2; ++mt) {
        int r = wm * 32 + mt * 16 + l15;
        a[mt] = *(const short8*)(As + r * 512 + (ka ^ ((r & 7) << 4)));
      }
      int kb = kk * 64 + lhi * 16;
      #pragma unroll
      for (int nt = 0; nt < 4; ++nt) {
        int r = wn * 64 + nt * 16 + l15;
        short8 b = *(const short8*)(Bs + r * 128 + (kb ^ ((r & 7) << 4)));
        acc2[0][nt] = __builtin_amdgcn_mfma_f32_16x16x32_bf16(a[0], b, acc2[0][nt], 0, 0, 0);
        acc2[1][nt] = __builtin_amdgcn_mfma_f32_16x16x32_bf16(a[1], b, acc2[1][nt], 0, 0, 0);
      }
    }
    __syncthreads();
  }

  #pragma unroll
  for (int mt = 0; mt < 2; ++mt)
    #pragma unroll
    for (int nt = 0; nt < 4; ++nt) {
      int col = wn * 64 + nt * 16 + l15;
      #pragma unroll
      for (int j = 0; j < 4; ++j) {
        int rloc = wm * 32 + mt * 16 + lhi * 4 + j;
        int row = row0 + rloc;
        if (row >= n) continue;
        float c = tanhf(acc2[mt][nt][j] + b2[col]);
        float uu = b2f(Us[rloc * 128 + col]);
        float hv = hf[(size_t)row * 128 + col];
        out[(size_t)row * 128 + col] = uu * hv + (1.f - uu) * c;
      }
    }
}

extern "C" void kernel_launch(void* const* d_in, const int* in_sizes, int n_in,
                              void* d_out, int out_size, void* d_ws, size_t ws_size,
                              hipStream_t stream) {
  const float* x     = (const float*)d_in[0];
  const void*  ei    = d_in[1];
  const float* h     = (const float*)d_in[3];
  const float* Wl    = (const float*)d_in[4];
  const float* Wr    = (const float*)d_in[5];
  const float* att   = (const float*)d_in[6];
  const float* bconv = (const float*)d_in[7];
  const float* W1    = (const float*)d_in[8];
  const float* b1    = (const float*)d_in[9];
  const float* W2    = (const float*)d_in[10];
  const float* b2    = (const float*)d_in[11];
  float* out = (float*)d_out;

  const int n = in_sizes[0] / 128;   // 50000
  const int E = in_sizes[1] / 2;     // 800000

  char* w = (char*)d_ws;
  size_t o = 0;
  auto alloc = [&](size_t bytes) {
    char* p = w + o;
    o += bytes;
    o = (o + 255) & ~(size_t)255;
    return p;
  };
  int* flag   = (int*)alloc(4);
  int* src32  = (int*)alloc((size_t)E * 4);
  int* dst32  = (int*)alloc((size_t)E * 4);
  int* deg    = (int*)alloc((size_t)(n + 1) * 4);
  int* off    = (int*)alloc((size_t)(n + 1) * 4);
  int* cursor = (int*)alloc((size_t)(n + 1) * 4);
  int* csr    = (int*)alloc((size_t)E * 4);
  unsigned short* xl   = (unsigned short*)alloc((size_t)n * 128 * 2);
  unsigned short* xr   = (unsigned short*)alloc((size_t)n * 128 * 2);
  unsigned short* fbuf = (unsigned short*)alloc((size_t)n * 128 * 2);
  unsigned short* Btxw = (unsigned short*)alloc(256 * 128 * 2);
  unsigned short* Bt1  = (unsigned short*)alloc(256 * 256 * 2);
  unsigned short* Bt2  = (unsigned short*)alloc(128 * 256 * 2);

  hipMemsetAsync(deg, 0, (size_t)(n + 1) * 4, stream);
  detect_kernel<<<1, 1024, 0, stream>>>((const unsigned int*)ei, 2LL * E, flag);
  convert_hist<<<(E + 255) / 256, 256, 0, stream>>>(ei, E, flag, src32, dst32, deg);
  scan_kernel<<<1, 1024, 0, stream>>>(deg, off, cursor, n);
  scatter_kernel<<<(E + 255) / 256, 256, 0, stream>>>(src32, dst32, cursor, csr, E);
  wprep<<<512, 256, 0, stream>>>(Wl, Wr, W1, W2, Btxw, Bt1, Bt2);

  int gblocks = (n + 63) / 64;
  gemm_xw<<<gblocks, 256, 0, stream>>>(x, Btxw, xl, xr, n);
  node_kernel<<<(n + 3) / 4, 256, 0, stream>>>((const unsigned int*)xl, (const unsigned int*)xr,
                                               att, bconv, off, csr,
                                               (unsigned int*)fbuf, n);
  gemm_fused<<<gblocks, 256, 0, stream>>>(fbuf, h, Bt1, Bt2, b1, b2, out, n);
}

// Round 5
// 232.961 us; speedup vs baseline: 2.3555x; 1.2757x over previous
//
#include <hip/hip_runtime.h>
#include <hip/hip_bf16.h>
#include <math.h>

typedef __attribute__((ext_vector_type(8))) short short8;
typedef __attribute__((ext_vector_type(4))) float floatx4;

__device__ __forceinline__ unsigned short f2b(float f) {
  unsigned int u = __builtin_bit_cast(unsigned int, f);
  u += 0x7fffu + ((u >> 16) & 1u);
  return (unsigned short)(u >> 16);
}
__device__ __forceinline__ float b2f(unsigned short s) {
  unsigned int u = ((unsigned int)s) << 16;
  return __builtin_bit_cast(float, u);
}
__device__ __forceinline__ float sigm(float v) { return 1.f / (1.f + __expf(-v)); }
__device__ __forceinline__ float tanh_fast(float y) {
  float t = __expf(2.f * y);
  return 1.f - 2.f / (t + 1.f);
}

// ---------------------------------------------------------------------------
// Edge preprocessing
// ---------------------------------------------------------------------------
__global__ __launch_bounds__(1024) void detect_kernel(const unsigned int* __restrict__ ei,
                                                      long long n_u32, int* __restrict__ flag) {
  __shared__ int any;
  if (threadIdx.x == 0) any = 0;
  __syncthreads();
  int nz = 0;
  for (int rep = 0; rep < 4; ++rep) {
    long long idx = 2LL * (threadIdx.x + rep * 1024) + 1;
    if (idx < n_u32 && ei[idx] != 0u) nz = 1;
  }
  if (nz) atomicOr(&any, 1);
  __syncthreads();
  if (threadIdx.x == 0) *flag = any;  // 1 -> int32 data, 0 -> int64 data
}

__device__ __forceinline__ void load_edge(const void* ei, int E, int flag, int i,
                                          int& s, int& d) {
  if (flag == 0) {
    const long long* p = (const long long*)ei;
    s = (int)p[i];
    d = (int)p[(long long)E + i];
  } else {
    const int* p = (const int*)ei;
    s = p[i];
    d = p[E + i];
  }
}

__global__ __launch_bounds__(256) void hist_kernel(const void* __restrict__ ei, int E,
                                                   const int* __restrict__ flag,
                                                   int* __restrict__ deg) {
  int i = blockIdx.x * 256 + threadIdx.x;
  if (i >= E) return;
  int s, d;
  load_edge(ei, E, *flag, i, s, d);
  atomicAdd(&deg[d], 1);
}

// parallel scan, 3 kernels: per-1024-block sums -> 1-wave scan -> finalize
__global__ __launch_bounds__(256) void scan_partial(const int* __restrict__ deg,
                                                    int* __restrict__ bsum, int n) {
  __shared__ int ws[4];
  int base = blockIdx.x * 1024 + threadIdx.x * 4;
  int lane = threadIdx.x & 63, wid = threadIdx.x >> 6;
  int tot = 0;
  #pragma unroll
  for (int k = 0; k < 4; ++k) {
    int i = base + k;
    if (i < n) tot += deg[i];
  }
  #pragma unroll
  for (int ofs = 1; ofs < 64; ofs <<= 1) tot += __shfl_xor(tot, ofs, 64);
  if (lane == 0) ws[wid] = tot;
  __syncthreads();
  if (threadIdx.x == 0) bsum[blockIdx.x] = ws[0] + ws[1] + ws[2] + ws[3];
}

__global__ __launch_bounds__(64) void scan_bsums(int* __restrict__ bsum, int nb) {
  int lane = threadIdx.x;
  int carry = 0;
  for (int base = 0; base < nb; base += 64) {
    int i = base + lane;
    int v = (i < nb) ? bsum[i] : 0;
    int s = v;
    #pragma unroll
    for (int ofs = 1; ofs < 64; ofs <<= 1) {
      int t = __shfl_up(s, ofs, 64);
      if (lane >= ofs) s += t;
    }
    if (i < nb) bsum[i] = s - v + carry;           // exclusive
    int tot = __shfl(s, 63, 64);
    carry += tot;
  }
}

__global__ __launch_bounds__(256) void scan_final(const int* __restrict__ deg,
                                                  const int* __restrict__ bsum,
                                                  int* __restrict__ off,
                                                  int* __restrict__ cursor, int n) {
  __shared__ int ws[4];
  int lane = threadIdx.x & 63, wid = threadIdx.x >> 6;
  int base = blockIdx.x * 1024 + threadIdx.x * 4;
  int v[4];
  int tot = 0;
  #pragma unroll
  for (int k = 0; k < 4; ++k) {
    int i = base + k;
    v[k] = (i < n) ? deg[i] : 0;
    tot += v[k];
  }
  int s = tot;
  #pragma unroll
  for (int ofs = 1; ofs < 64; ofs <<= 1) {
    int t = __shfl_up(s, ofs, 64);
    if (lane >= ofs) s += t;
  }
  if (lane == 63) ws[wid] = s;
  __syncthreads();
  int wpre = 0;
  for (int ww = 0; ww < wid; ++ww) wpre += ws[ww];
  int p = bsum[blockIdx.x] + wpre + (s - tot);     // exclusive prefix of this thread
  if (blockIdx.x == 0 && threadIdx.x == 0) { off[0] = 0; cursor[0] = 0; }
  #pragma unroll
  for (int k = 0; k < 4; ++k) {
    int i = base + k;
    p += v[k];
    if (i < n) { off[i + 1] = p; cursor[i + 1] = p; }
  }
}

__global__ __launch_bounds__(256) void scatter_kernel(const void* __restrict__ ei, int E,
                                                      const int* __restrict__ flag,
                                                      int* __restrict__ cursor,
                                                      int* __restrict__ csr) {
  int i = blockIdx.x * 256 + threadIdx.x;
  if (i >= E) return;
  int s, d;
  load_edge(ei, E, *flag, i, s, d);
  int pos = atomicAdd(&cursor[d], 1);
  csr[pos] = s;
}

// weights -> transposed bf16 (B^T [N][K])
__global__ __launch_bounds__(256) void wprep(const float* __restrict__ Wl,
                                             const float* __restrict__ Wr,
                                             const float* __restrict__ W1,
                                             const float* __restrict__ W2,
                                             unsigned short* __restrict__ Btxw,
                                             unsigned short* __restrict__ Bt1,
                                             unsigned short* __restrict__ Bt2) {
  int idx = blockIdx.x * 256 + threadIdx.x;
  if (idx < 32768) {                         // Btxw[256][128]
    int nn = idx >> 7, k = idx & 127;
    float v = (nn < 128) ? Wl[k * 128 + nn] : Wr[k * 128 + (nn - 128)];
    Btxw[nn * 128 + k] = f2b(v);
  } else if (idx < 98304) {                  // Bt1[256][256] = W1^T
    int loc = idx - 32768;
    int nn = loc >> 8, k = loc & 255;
    Bt1[nn * 256 + k] = f2b(W1[k * 256 + nn]);
  } else {                                   // Bt2[128][256] = W2^T
    int loc = idx - 98304;
    int nn = loc >> 8, k = loc & 255;
    Bt2[nn * 256 + k] = f2b(W2[k * 128 + nn]);
  }
}

// ---------------------------------------------------------------------------
// xl|xr = x @ [Wl|Wr].  Block 64 rows, 4 waves; wave = 64 rows x 64 cols.
// Full B (256x128) resident in LDS; one barrier pair; 64 MFMA / 32 ds_read.
// Staging rule (rule #21): source at LINEAR offset, LDS dest swizzled;
// reads swizzle with the same XOR.
// ---------------------------------------------------------------------------
__global__ __launch_bounds__(256) void gemm_xw(const float* __restrict__ x,
                                               const unsigned short* __restrict__ Bt,
                                               unsigned short* __restrict__ xl,
                                               unsigned short* __restrict__ xr, int n) {
  __shared__ char As[64 * 256];    // 64 rows x 128 bf16, swizzled
  __shared__ char Bs[256 * 256];   // 256 N-rows x 128 K bf16, swizzled
  int t = threadIdx.x;
  int w = t >> 6, l = t & 63;
  int row0 = blockIdx.x * 64;
  int l15 = l & 15, lhi = l >> 4;

  // stage A from f32: src linear (slot*8 floats), dest swizzled
  #pragma unroll
  for (int u_ = 0; u_ < 4; ++u_) {
    int unit = t + u_ * 256;
    int r = unit >> 4, slot = unit & 15;
    int grow = row0 + r;
    uint4 o = make_uint4(0, 0, 0, 0);
    if (grow < n) {
      const float* s = x + (size_t)grow * 128 + slot * 8;
      float4 f0 = *(const float4*)s, f1 = *(const float4*)(s + 4);
      o.x = (unsigned)f2b(f0.x) | ((unsigned)f2b(f0.y) << 16);
      o.y = (unsigned)f2b(f0.z) | ((unsigned)f2b(f0.w) << 16);
      o.z = (unsigned)f2b(f1.x) | ((unsigned)f2b(f1.y) << 16);
      o.w = (unsigned)f2b(f1.z) | ((unsigned)f2b(f1.w) << 16);
    }
    *(uint4*)(As + r * 256 + ((slot * 16) ^ ((r & 7) << 4))) = o;
  }
  // stage full B: src linear, dest swizzled
  #pragma unroll
  for (int u_ = 0; u_ < 16; ++u_) {
    int unit = t + u_ * 256;
    int r = unit >> 4, slot = unit & 15;
    uint4 v = *(const uint4*)(Bt + (size_t)r * 128 + slot * 8);
    *(uint4*)(Bs + r * 256 + ((slot * 16) ^ ((r & 7) << 4))) = v;
  }
  __syncthreads();

  floatx4 acc[4][4];
  #pragma unroll
  for (int mt = 0; mt < 4; ++mt)
    #pragma unroll
    for (int nt = 0; nt < 4; ++nt) acc[mt][nt] = (floatx4){0.f, 0.f, 0.f, 0.f};

  #pragma unroll
  for (int kk = 0; kk < 4; ++kk) {
    int ko = kk * 64 + lhi * 16;
    short8 a[4];
    #pragma unroll
    for (int mt = 0; mt < 4; ++mt) {
      int r = mt * 16 + l15;
      a[mt] = *(const short8*)(As + r * 256 + (ko ^ ((r & 7) << 4)));
    }
    #pragma unroll
    for (int nt = 0; nt < 4; ++nt) {
      int r = w * 64 + nt * 16 + l15;
      short8 b = *(const short8*)(Bs + r * 256 + (ko ^ ((r & 7) << 4)));
      #pragma unroll
      for (int mt = 0; mt < 4; ++mt)
        acc[mt][nt] = __builtin_amdgcn_mfma_f32_16x16x32_bf16(a[mt], b, acc[mt][nt], 0, 0, 0);
    }
  }

  #pragma unroll
  for (int mt = 0; mt < 4; ++mt)
    #pragma unroll
    for (int nt = 0; nt < 4; ++nt) {
      int col = w * 64 + nt * 16 + l15;
      int rbase = row0 + mt * 16 + lhi * 4;
      #pragma unroll
      for (int j = 0; j < 4; ++j) {
        int row = rbase + j;
        if (row >= n) continue;
        unsigned short v = f2b(acc[mt][nt][j]);
        if (col < 128) xl[(size_t)row * 128 + col] = v;
        else           xr[(size_t)row * 128 + (col - 128)] = v;
      }
    }
}

// ---------------------------------------------------------------------------
// One wave per node; lane l owns dims (2l, 2l+1); head = l>>4.
// Unroll-4: batch 4 gathers, then 4 reduce chains.
// ---------------------------------------------------------------------------
__global__ __launch_bounds__(256) void node_kernel(const unsigned int* __restrict__ xl32,
                                                   const unsigned int* __restrict__ xr32,
                                                   const float* __restrict__ att,
                                                   const float* __restrict__ bias,
                                                   const int* __restrict__ off,
                                                   const int* __restrict__ csr,
                                                   unsigned int* __restrict__ fout, int n) {
  int wid = threadIdx.x >> 6, lane = threadIdx.x & 63;
  int node = blockIdx.x * 4 + wid;
  if (node >= n) return;
  float a0 = att[2 * lane], a1 = att[2 * lane + 1];
  unsigned int xrp = xr32[(size_t)node * 64 + lane];
  float xr0 = b2f((unsigned short)xrp);
  float xr1 = b2f((unsigned short)(xrp >> 16));
  float num0 = 0.f, num1 = 0.f, den = 0.f;
  int beg = off[node], end = off[node + 1];

  auto comp = [&](unsigned int g) {
    float x0 = b2f((unsigned short)g), x1 = b2f((unsigned short)(g >> 16));
    float m0 = x0 + xr0, m1 = x1 + xr1;
    float l0 = fmaxf(m0, 0.2f * m0), l1 = fmaxf(m1, 0.2f * m1);
    float p = fmaf(l1, a1, l0 * a0);
    #pragma unroll
    for (int mask = 1; mask < 16; mask <<= 1) p += __shfl_xor(p, mask, 64);
    float wgt = __expf(p);
    num0 = fmaf(wgt, x0, num0);
    num1 = fmaf(wgt, x1, num1);
    den += wgt;
  };

  comp(xl32[(size_t)node * 64 + lane]);  // self loop
  for (int base = beg; base < end; base += 64) {
    int cnt = end - base;
    if (cnt > 64) cnt = 64;
    int my = csr[base + (lane < cnt ? lane : 0)];
    int i = 0;
    for (; i + 4 <= cnt; i += 4) {
      int s0 = __builtin_amdgcn_readlane(my, i);
      int s1 = __builtin_amdgcn_readlane(my, i + 1);
      int s2 = __builtin_amdgcn_readlane(my, i + 2);
      int s3 = __builtin_amdgcn_readlane(my, i + 3);
      unsigned int g0 = xl32[(size_t)s0 * 64 + lane];
      unsigned int g1 = xl32[(size_t)s1 * 64 + lane];
      unsigned int g2 = xl32[(size_t)s2 * 64 + lane];
      unsigned int g3 = xl32[(size_t)s3 * 64 + lane];
      comp(g0); comp(g1); comp(g2); comp(g3);
    }
    for (; i < cnt; ++i) {
      int s0 = __builtin_amdgcn_readlane(my, i);
      comp(xl32[(size_t)s0 * 64 + lane]);
    }
  }
  float inv = 1.f / (den + 1e-16f);
  float v0 = num0 * inv + bias[2 * lane];
  float v1 = num1 * inv + bias[2 * lane + 1];
  fout[(size_t)node * 64 + lane] = (unsigned)f2b(sigm(v0)) | ((unsigned)f2b(sigm(v1)) << 16);
}

// ---------------------------------------------------------------------------
// Fused GRU GEMMs.  Block 64 rows, 4 waves.
// Phase1 (N=256): wave = 64 rows x 64 cols. Phase2 (N=128): 64 x 32.
// ---------------------------------------------------------------------------
__global__ __launch_bounds__(256) void gemm_fused(const unsigned short* __restrict__ fbuf,
                                                  const float* __restrict__ hf,
                                                  const unsigned short* __restrict__ Bt1,
                                                  const unsigned short* __restrict__ Bt2,
                                                  const float* __restrict__ b1,
                                                  const float* __restrict__ b2,
                                                  float* __restrict__ out, int n) {
  __shared__ char As[64 * 512];           // [f|h] 64 rows x 256 bf16, swizzled
  __shared__ char Bs[256 * 128];          // B K-chunk, swizzled
  __shared__ unsigned short Us[64 * 128]; // u gate
  int t = threadIdx.x;
  int w = t >> 6, l = t & 63;
  int row0 = blockIdx.x * 64;
  int l15 = l & 15, lhi = l >> 4;

  // stage A = [f | h]: src linear (koff), dest swizzled
  #pragma unroll
  for (int u_ = 0; u_ < 8; ++u_) {
    int unit = t + u_ * 256;
    int r = unit >> 5, slot = unit & 31;
    int koff = slot * 16;
    int grow = row0 + r;
    uint4 v = make_uint4(0, 0, 0, 0);
    if (grow < n) {
      if (koff < 256) {
        v = *(const uint4*)(fbuf + (size_t)grow * 128 + koff / 2);
      } else {
        const float* s = hf + (size_t)grow * 128 + (koff - 256) / 2;
        float4 f0 = *(const float4*)s, f1 = *(const float4*)(s + 4);
        v.x = (unsigned)f2b(f0.x) | ((unsigned)f2b(f0.y) << 16);
        v.y = (unsigned)f2b(f0.z) | ((unsigned)f2b(f0.w) << 16);
        v.z = (unsigned)f2b(f1.x) | ((unsigned)f2b(f1.y) << 16);
        v.w = (unsigned)f2b(f1.z) | ((unsigned)f2b(f1.w) << 16);
      }
    }
    *(uint4*)(As + r * 512 + (koff ^ ((r & 7) << 4))) = v;
  }

  // ---- phase 1: K=256, N=256 ----
  floatx4 acc[4][4];
  #pragma unroll
  for (int mt = 0; mt < 4; ++mt)
    #pragma unroll
    for (int nt = 0; nt < 4; ++nt) acc[mt][nt] = (floatx4){0.f, 0.f, 0.f, 0.f};

  for (int ks = 0; ks < 4; ++ks) {
    #pragma unroll
    for (int u_ = 0; u_ < 8; ++u_) {            // 256 rows x 128 B chunk
      int unit = t + u_ * 256;
      int r = unit >> 3, b16 = unit & 7;
      uint4 v = *(const uint4*)(Bt1 + (size_t)r * 256 + ks * 64 + b16 * 8);
      *(uint4*)(Bs + r * 128 + ((b16 * 16) ^ ((r & 7) << 4))) = v;
    }
    __syncthreads();
    #pragma unroll
    for (int kk = 0; kk < 2; ++kk) {
      int ka = ks * 128 + kk * 64 + lhi * 16;
      int kb = kk * 64 + lhi * 16;
      short8 a[4];
      #pragma unroll
      for (int mt = 0; mt < 4; ++mt) {
        int r = mt * 16 + l15;
        a[mt] = *(const short8*)(As + r * 512 + (ka ^ ((r & 7) << 4)));
      }
      #pragma unroll
      for (int nt = 0; nt < 4; ++nt) {
        int r = w * 64 + nt * 16 + l15;
        short8 b = *(const short8*)(Bs + r * 128 + (kb ^ ((r & 7) << 4)));
        #pragma unroll
        for (int mt = 0; mt < 4; ++mt)
          acc[mt][nt] = __builtin_amdgcn_mfma_f32_16x16x32_bf16(a[mt], b, acc[mt][nt], 0, 0, 0);
      }
    }
    __syncthreads();
  }

  // phase-1 epilogue: cols<128 -> rh overwrites h half of As (swizzled); cols>=128 -> Us
  #pragma unroll
  for (int mt = 0; mt < 4; ++mt)
    #pragma unroll
    for (int nt = 0; nt < 4; ++nt) {
      int col = w * 64 + nt * 16 + l15;
      #pragma unroll
      for (int j = 0; j < 4; ++j) {
        int rloc = mt * 16 + lhi * 4 + j;
        float s = sigm(acc[mt][nt][j] + b1[col]);
        if (col < 128) {
          int byteoff = (256 + col * 2) ^ ((rloc & 7) << 4);
          char* p = As + rloc * 512 + byteoff;
          unsigned short hv = *(unsigned short*)p;
          *(unsigned short*)p = f2b(s * b2f(hv));
        } else {
          Us[rloc * 128 + (col - 128)] = f2b(s);
        }
      }
    }
  __syncthreads();

  // ---- phase 2: K=256, N=128 ----
  floatx4 acc2[4][2];
  #pragma unroll
  for (int mt = 0; mt < 4; ++mt)
    #pragma unroll
    for (int nt = 0; nt < 2; ++nt) acc2[mt][nt] = (floatx4){0.f, 0.f, 0.f, 0.f};

  for (int ks = 0; ks < 4; ++ks) {
    #pragma unroll
    for (int u_ = 0; u_ < 4; ++u_) {            // 128 rows x 128 B chunk
      int unit = t + u_ * 256;
      int r = unit >> 3, b16 = unit & 7;
      uint4 v = *(const uint4*)(Bt2 + (size_t)r * 256 + ks * 64 + b16 * 8);
      *(uint4*)(Bs + r * 128 + ((b16 * 16) ^ ((r & 7) << 4))) = v;
    }
    __syncthreads();
    #pragma unroll
    for (int kk = 0; kk < 2; ++kk) {
      int ka = ks * 128 + kk * 64 + lhi * 16;
      int kb = kk * 64 + lhi * 16;
      short8 a[4];
      #pragma unroll
      for (int mt = 0; mt < 4; ++mt) {
        int r = mt * 16 + l15;
        a[mt] = *(const short8*)(As + r * 512 + (ka ^ ((r & 7) << 4)));
      }
      #pragma unroll
      for (int nt = 0; nt < 2; ++nt) {
        int r = w * 32 + nt * 16 + l15;
        short8 b = *(const short8*)(Bs + r * 128 + (kb ^ ((r & 7) << 4)));
        #pragma unroll
        for (int mt = 0; mt < 4; ++mt)
          acc2[mt][nt] = __builtin_amdgcn_mfma_f32_16x16x32_bf16(a[mt], b, acc2[mt][nt], 0, 0, 0);
      }
    }
    __syncthreads();
  }

  #pragma unroll
  for (int mt = 0; mt < 4; ++mt)
    #pragma unroll
    for (int nt = 0; nt < 2; ++nt) {
      int col = w * 32 + nt * 16 + l15;
      #pragma unroll
      for (int j = 0; j < 4; ++j) {
        int rloc = mt * 16 + lhi * 4 + j;
        int row = row0 + rloc;
        if (row >= n) continue;
        float c = tanh_fast(acc2[mt][nt][j] + b2[col]);
        float uu = b2f(Us[rloc * 128 + col]);
        float hv = hf[(size_t)row * 128 + col];
        out[(size_t)row * 128 + col] = uu * hv + (1.f - uu) * c;
      }
    }
}

extern "C" void kernel_launch(void* const* d_in, const int* in_sizes, int n_in,
                              void* d_out, int out_size, void* d_ws, size_t ws_size,
                              hipStream_t stream) {
  const float* x     = (const float*)d_in[0];
  const void*  ei    = d_in[1];
  const float* h     = (const float*)d_in[3];
  const float* Wl    = (const float*)d_in[4];
  const float* Wr    = (const float*)d_in[5];
  const float* att   = (const float*)d_in[6];
  const float* bconv = (const float*)d_in[7];
  const float* W1    = (const float*)d_in[8];
  const float* b1    = (const float*)d_in[9];
  const float* W2    = (const float*)d_in[10];
  const float* b2    = (const float*)d_in[11];
  float* out = (float*)d_out;

  const int n = in_sizes[0] / 128;   // 50000
  const int E = in_sizes[1] / 2;     // 800000

  char* w = (char*)d_ws;
  size_t o = 0;
  auto alloc = [&](size_t bytes) {
    char* p = w + o;
    o += bytes;
    o = (o + 255) & ~(size_t)255;
    return p;
  };
  int* flag   = (int*)alloc(4);
  int* deg    = (int*)alloc((size_t)(n + 1) * 4);
  int* off    = (int*)alloc((size_t)(n + 1) * 4);
  int* cursor = (int*)alloc((size_t)(n + 1) * 4);
  int* bsum   = (int*)alloc(1024 * 4);
  int* csr    = (int*)alloc((size_t)E * 4);
  unsigned short* xl   = (unsigned short*)alloc((size_t)n * 128 * 2);
  unsigned short* xr   = (unsigned short*)alloc((size_t)n * 128 * 2);
  unsigned short* fbuf = (unsigned short*)alloc((size_t)n * 128 * 2);
  unsigned short* Btxw = (unsigned short*)alloc(256 * 128 * 2);
  unsigned short* Bt1  = (unsigned short*)alloc(256 * 256 * 2);
  unsigned short* Bt2  = (unsigned short*)alloc(128 * 256 * 2);

  hipMemsetAsync(deg, 0, (size_t)(n + 1) * 4, stream);
  detect_kernel<<<1, 1024, 0, stream>>>((const unsigned int*)ei, 2LL * E, flag);
  hist_kernel<<<(E + 255) / 256, 256, 0, stream>>>(ei, E, flag, deg);
  int nb = (n + 1023) / 1024;
  scan_partial<<<nb, 256, 0, stream>>>(deg, bsum, n);
  scan_bsums<<<1, 64, 0, stream>>>(bsum, nb);
  scan_final<<<nb, 256, 0, stream>>>(deg, bsum, off, cursor, n);
  scatter_kernel<<<(E + 255) / 256, 256, 0, stream>>>(ei, E, flag, cursor, csr);
  wprep<<<512, 256, 0, stream>>>(Wl, Wr, W1, W2, Btxw, Bt1, Bt2);

  int gblocks = (n + 63) / 64;
  gemm_xw<<<gblocks, 256, 0, stream>>>(x, Btxw, xl, xr, n);
  node_kernel<<<(n + 3) / 4, 256, 0, stream>>>((const unsigned int*)xl, (const unsigned int*)xr,
                                               att, bconv, off, csr,
                                               (unsigned int*)fbuf, n);
  gemm_fused<<<gblocks, 256, 0, stream>>>(fbuf, h, Bt1, Bt2, b1, b2, out, n);
}